// Round 6
// baseline (182.475 us; speedup 1.0000x reference)
//
#include <hip/hip_runtime.h>
#include <hip/hip_bf16.h>

// TT embedding bag.
// idx = pair*50 + d2 (pair<2500, d2<50). emb depends only on idx value:
//   emb_table[idx][kk*8+z] = sum_r t[pair][kk][r] * core2[d2][r*8+z]
//   t[pair][kk=x*4+y][s]   = sum_r core0[d0][x*32+r] * core1[d1][r*128+y*32+s]
// Phase A: dense build of emb_table (125000 x 128, bf16) = 2500 blocks, one pair each.
// Phase B: LDS-staged gathers (emb_table + cache_table) + segmented sum, atomic flush.

#define PAIRS 2500
#define CHT 128   // TT positions per sum-block (rows of 256B)
#define CHC 64    // cached positions per sum-block (rows of 512B)

typedef unsigned int u32;
typedef unsigned short u16;

__device__ __forceinline__ float bfu(u16 u) { return __uint_as_float(((u32)u) << 16); }
__device__ __forceinline__ u16 f2bf(float x) {
  __hip_bfloat16 h = __float2bfloat16(x);
  return *reinterpret_cast<u16*>(&h);
}

__device__ __forceinline__ void gload_lds16(const void* g, void* l) {
  __builtin_amdgcn_global_load_lds(
      (const __attribute__((address_space(1))) u32*)g,
      (__attribute__((address_space(3))) u32*)l, 16, 0, 0);
}

// ---------------- Phase A ----------------
__global__ __launch_bounds__(512, 4) void build_emb_table_kernel(
    const float* __restrict__ core0, const float* __restrict__ core1,
    const float* __restrict__ core2, u16* __restrict__ emb_t) {
  __shared__ float ts[512];          // t[kk*32+s]
  __shared__ float c0s[128];
  __shared__ float c1s[4096];
  __shared__ float chat[50 * 288];   // chat[d2*288 + z*36 + r], padded rows (16B aligned)
  const int p = blockIdx.x;
  const int d0 = p / 50, d1 = p - d0 * 50;
  const int tid = threadIdx.x;

  // stage core0 row, core1 row, and all of core2 (transposed) into LDS
  {
    const float4* s1 = reinterpret_cast<const float4*>(core1 + (size_t)d1 * 4096);
    float4* dst = reinterpret_cast<float4*>(c1s);
#pragma unroll
    for (int i = 0; i < 2; ++i) dst[tid + i * 512] = s1[tid + i * 512];
    if (tid < 32)
      reinterpret_cast<float4*>(c0s)[tid] =
          reinterpret_cast<const float4*>(core0 + (size_t)d0 * 128)[tid];
#pragma unroll
    for (int j = 0; j < 25; ++j) {
      const int q = tid + j * 512;           // 12800 = 25*512 exact
      const float v = core2[q];
      const int d2 = q >> 8, rem = q & 255, r = rem >> 3, z = rem & 7;
      chat[d2 * 288 + z * 36 + r] = v;
    }
  }
  __syncthreads();

  // t = 16x32, one element per thread
  {
    const int kk = tid >> 5, s = tid & 31;
    const int x = kk >> 2, y = kk & 3;
    float acc = 0.f;
#pragma unroll
    for (int r = 0; r < 32; ++r)
      acc += c0s[x * 32 + r] * c1s[r * 128 + y * 32 + s];
    ts[kk * 32 + s] = acc;
  }
  __syncthreads();

  // thread tau<400 owns column (d2, z): C-col in 32 regs, t-row via LDS broadcast
  if (tid < 400) {
    const int d2 = tid >> 3, z = tid & 7;
    float4 c[8];
    const float4* cp = reinterpret_cast<const float4*>(chat + d2 * 288 + z * 36);
#pragma unroll
    for (int rq = 0; rq < 8; ++rq) c[rq] = cp[rq];
    const float4* t4 = reinterpret_cast<const float4*>(ts);
    u16* op = emb_t + (((size_t)(p * 50 + d2)) << 7) + z;
#pragma unroll
    for (int kk = 0; kk < 16; ++kk) {
      float s = 0.f;
#pragma unroll
      for (int rq = 0; rq < 8; ++rq) {
        const float4 tb = t4[kk * 8 + rq];   // wave-uniform address -> broadcast
        s += tb.x * c[rq].x + tb.y * c[rq].y + tb.z * c[rq].z + tb.w * c[rq].w;
      }
      op[kk * 8] = f2bf(s);
    }
  }
}

// ---------------- Phase B ----------------
__device__ __forceinline__ int bag_search(const int* __restrict__ offs,
                                          int nbags, int p) {
  int lo = 0, hi = nbags;
  while (hi - lo > 1) {
    int m = (lo + hi) >> 1;
    if (offs[m] <= p) lo = m; else hi = m;
  }
  return lo;
}

__global__ __launch_bounds__(256, 4) void sum_kernel(
    const int* __restrict__ indices, const int* __restrict__ offsets,
    const int* __restrict__ cached_indices, const int* __restrict__ cached_offsets,
    const float* __restrict__ cache_table, const u16* __restrict__ emb_t,
    float* __restrict__ out, int n, int nbags, int ntt_blocks) {
  __shared__ __align__(16) u16 sdat[CHT * 128];  // 32KB; cache part uses as float[CHC*128]
  __shared__ int sidx[CHT];
  __shared__ int sbag[CHT];
  const int tid = threadIdx.x;
  const int bid = blockIdx.x;
  const int lane = tid & 63;
  const int w = tid >> 6;

  if (bid < ntt_blocks) {
    // ---- TT gather: 256B bf16 rows from emb_table ----
    const int base = bid * CHT;
    const int count = min(CHT, n - base);
    if (tid < count) {
      sidx[tid] = indices[base + tid];
      sbag[tid] = bag_search(offsets, nbags, base + tid);
    }
    __syncthreads();
    if (count == CHT) {
      u32* ldsb = reinterpret_cast<u32*>(sdat);
#pragma unroll
      for (int j = 0; j < 8; ++j) {
        const int r4 = w * 32 + j * 4;                 // stage rows r4..r4+3 in one inst
        const int row = r4 + (lane >> 4);
        const char* src = reinterpret_cast<const char*>(emb_t) +
                          (((size_t)sidx[row]) << 8) + ((lane & 15) << 4);
        gload_lds16(src, ldsb + r4 * 64);
      }
    } else {
      for (int r = w; r < count; r += 4) {
        reinterpret_cast<u32*>(sdat)[r * 64 + lane] =
            reinterpret_cast<const u32*>(emb_t)[(((size_t)sidx[r]) << 6) + lane];
      }
    }
    __syncthreads();
    const int k = tid & 127, h = tid >> 7;
    const int rlo = h * (CHT / 2);
    const int rhi = min(count, rlo + CHT / 2);
    float acc = 0.f;
    for (int i = rlo; i < rhi; ++i) {
      acc += bfu(sdat[i * 128 + k]);
      if (i + 1 == rhi || sbag[i + 1] != sbag[i]) {
        atomicAdd(out + (((size_t)sbag[i]) << 7) + k, acc);
        acc = 0.f;
      }
    }
  } else {
    // ---- cache gather: 512B fp32 rows from cache_table ----
    const int cb = bid - ntt_blocks;
    const int base = cb * CHC;
    const int count = min(CHC, n - base);
    float* sfl = reinterpret_cast<float*>(sdat);
    if (tid < count) {
      sidx[tid] = cached_indices[base + tid];
      sbag[tid] = bag_search(cached_offsets, nbags, base + tid);
    }
    __syncthreads();
    if (count == CHC) {
#pragma unroll
      for (int j = 0; j < 8; ++j) {
        const int r2 = w * 16 + j * 2;                 // stage rows r2, r2+1 in one inst
        const int row = r2 + (lane >> 5);
        const char* src = reinterpret_cast<const char*>(cache_table) +
                          (((size_t)sidx[row]) << 9) + ((lane & 31) << 4);
        gload_lds16(src, sfl + r2 * 128);
      }
    } else {
      for (int r = w; r < count; r += 4) {
        reinterpret_cast<float2*>(sfl + r * 128)[lane] =
            reinterpret_cast<const float2*>(cache_table + (((size_t)sidx[r]) << 7))[lane];
      }
    }
    __syncthreads();
    const int k = tid & 127, h = tid >> 7;
    const int rlo = h * (CHC / 2);
    const int rhi = min(count, rlo + CHC / 2);
    float acc = 0.f;
    for (int i = rlo; i < rhi; ++i) {
      acc += sfl[i * 128 + k];
      if (i + 1 == rhi || sbag[i + 1] != sbag[i]) {
        atomicAdd(out + (((size_t)sbag[i]) << 7) + k, acc);
        acc = 0.f;
      }
    }
  }
}

extern "C" void kernel_launch(void* const* d_in, const int* in_sizes, int n_in,
                              void* d_out, int out_size, void* d_ws, size_t ws_size,
                              hipStream_t stream) {
  const int* indices        = (const int*)d_in[0];
  const int* offsets        = (const int*)d_in[1];
  const int* cached_indices = (const int*)d_in[2];
  const int* cached_offsets = (const int*)d_in[3];
  const float* core0        = (const float*)d_in[4];
  const float* core1        = (const float*)d_in[5];
  const float* core2        = (const float*)d_in[6];
  const float* cache_table  = (const float*)d_in[7];
  float* out = (float*)d_out;

  const int n = in_sizes[0];             // 204800
  const int nbags = in_sizes[1] - 1;     // 4096

  u16* emb_t = (u16*)d_ws;               // 125000*128*2 = 32,000,000 B

  hipMemsetAsync(out, 0, (size_t)out_size * sizeof(float), stream);

  build_emb_table_kernel<<<PAIRS, 512, 0, stream>>>(core0, core1, core2, emb_t);

  const int ntt = (n + CHT - 1) / CHT;   // 1600
  const int nc  = (n + CHC - 1) / CHC;   // 3200
  sum_kernel<<<ntt + nc, 256, 0, stream>>>(
      indices, offsets, cached_indices, cached_offsets, cache_table, emb_t,
      out, n, nbags, ntt);
}

// Round 7
// 165.927 us; speedup vs baseline: 1.0997x; 1.0997x over previous
//
#include <hip/hip_runtime.h>
#include <hip/hip_bf16.h>

// TT embedding bag.
// idx = pair*50 + d2 (pair<2500, d2<50). emb depends only on idx value:
//   emb_table[idx][kk*8+z] = sum_r t[pair][kk][r] * core2[d2][r*8+z]
//   t[pair][kk=x*4+y][s]   = sum_r core0[d0][x*32+r] * core1[d1][r*128+y*32+s]
// Phase 0: chat[d2][z][r] = core2[d2][r*8+z], rows padded to 36 floats (57.6KB, L2-hot)
// Phase A: emb_table (125000 x 128, bf16): 2500 blocks (one pair), chat read from L2.
// Phase B: LDS-staged gathers + segmented sum, 8 blocks/CU for latency hiding.

#define PAIRS 2500
#define CHT 64    // TT positions per sum-block (rows of 256B)
#define CHC 32    // cached positions per sum-block (rows of 512B)

typedef unsigned int u32;
typedef unsigned short u16;

__device__ __forceinline__ float bfu(u16 u) { return __uint_as_float(((u32)u) << 16); }
__device__ __forceinline__ u16 f2bf(float x) {
  __hip_bfloat16 h = __float2bfloat16(x);
  return *reinterpret_cast<u16*>(&h);
}

__device__ __forceinline__ void gload_lds16(const void* g, void* l) {
  __builtin_amdgcn_global_load_lds(
      (const __attribute__((address_space(1))) u32*)g,
      (__attribute__((address_space(3))) u32*)l, 16, 0, 0);
}

// ---------------- Phase 0: core2 transpose ----------------
__global__ __launch_bounds__(256) void chat_kernel(const float* __restrict__ core2,
                                                   float* __restrict__ chat) {
  const int d2 = blockIdx.x;
  const int tid = threadIdx.x;
  const int r = tid >> 3, z = tid & 7;
  chat[d2 * 288 + z * 36 + r] = core2[d2 * 256 + r * 8 + z];
}

// ---------------- Phase A ----------------
__global__ __launch_bounds__(512, 4) void build_emb_kernel(
    const float* __restrict__ core0, const float* __restrict__ core1,
    const float* __restrict__ chat, u16* __restrict__ emb_t) {
  __shared__ float c0s[128];
  __shared__ float c1s[4096];
  __shared__ float ts[512];          // t[kk*32+s]
  const int p = blockIdx.x;
  const int d0 = p / 50, d1 = p - d0 * 50;
  const int tid = threadIdx.x;

  // stage core1 row (16KB) + core0 row (512B)
  {
    const float4* s1 = reinterpret_cast<const float4*>(core1 + (size_t)d1 * 4096);
    float4* dst = reinterpret_cast<float4*>(c1s);
    dst[tid] = s1[tid];
    dst[tid + 512] = s1[tid + 512];
    if (tid < 32)
      reinterpret_cast<float4*>(c0s)[tid] =
          reinterpret_cast<const float4*>(core0 + (size_t)d0 * 128)[tid];
  }
  __syncthreads();

  // t = 16x32, one element per thread
  {
    const int kk = tid >> 5, s = tid & 31;
    const int x = kk >> 2, y = kk & 3;
    float acc = 0.f;
#pragma unroll
    for (int r = 0; r < 32; ++r)
      acc += c0s[x * 32 + r] * c1s[r * 128 + y * 32 + s];
    ts[kk * 32 + s] = acc;
  }
  __syncthreads();

  // thread tau<400 owns output column (d2, z): chat col from L2 into regs,
  // t rows via LDS wave-broadcast.
  if (tid < 400) {
    const int d2 = tid >> 3, z = tid & 7;
    float4 c[8];
    const float4* cp = reinterpret_cast<const float4*>(chat + d2 * 288 + z * 36);
#pragma unroll
    for (int rq = 0; rq < 8; ++rq) c[rq] = cp[rq];
    const float4* t4 = reinterpret_cast<const float4*>(ts);
    u16* op = emb_t + (((size_t)(p * 50 + d2)) << 7) + z;
#pragma unroll
    for (int kk = 0; kk < 16; ++kk) {
      float s = 0.f;
#pragma unroll
      for (int rq = 0; rq < 8; ++rq) {
        const float4 tb = t4[kk * 8 + rq];   // wave-uniform -> broadcast, no conflict
        s += tb.x * c[rq].x + tb.y * c[rq].y + tb.z * c[rq].z + tb.w * c[rq].w;
      }
      op[kk * 8] = f2bf(s);
    }
  }
}

// ---------------- Phase B ----------------
__device__ __forceinline__ int bag_search(const int* __restrict__ offs,
                                          int nbags, int p) {
  int lo = 0, hi = nbags;
  while (hi - lo > 1) {
    int m = (lo + hi) >> 1;
    if (offs[m] <= p) lo = m; else hi = m;
  }
  return lo;
}

__global__ __launch_bounds__(256, 8) void sum_kernel(
    const int* __restrict__ indices, const int* __restrict__ offsets,
    const int* __restrict__ cached_indices, const int* __restrict__ cached_offsets,
    const float* __restrict__ cache_table, const u16* __restrict__ emb_t,
    float* __restrict__ out, int n, int nbags, int ntt_blocks) {
  __shared__ __align__(16) u16 sdat[CHT * 128];  // 16KB; cache part uses as float[CHC*128]
  __shared__ int sidx[CHT];
  __shared__ int sbag[CHT];
  const int tid = threadIdx.x;
  const int bid = blockIdx.x;
  const int lane = tid & 63;
  const int w = tid >> 6;

  if (bid < ntt_blocks) {
    // ---- TT gather: 256B bf16 rows from emb_table ----
    const int base = bid * CHT;
    const int count = min(CHT, n - base);
    if (tid < count) {
      sidx[tid] = indices[base + tid];
      sbag[tid] = bag_search(offsets, nbags, base + tid);
    }
    __syncthreads();
    if (count == CHT) {
      u32* ldsb = reinterpret_cast<u32*>(sdat);
#pragma unroll
      for (int j = 0; j < 4; ++j) {
        const int r4 = w * 16 + j * 4;                 // 4 rows per instruction
        const int row = r4 + (lane >> 4);
        const char* src = reinterpret_cast<const char*>(emb_t) +
                          (((size_t)sidx[row]) << 8) + ((lane & 15) << 4);
        gload_lds16(src, ldsb + r4 * 64);
      }
    } else {
      for (int r = w; r < count; r += 4) {
        reinterpret_cast<u32*>(sdat)[r * 64 + lane] =
            reinterpret_cast<const u32*>(emb_t)[(((size_t)sidx[r]) << 6) + lane];
      }
    }
    __syncthreads();
    const int k = tid & 127, h = tid >> 7;
    const int rlo = h * (CHT / 2);
    const int rhi = min(count, rlo + CHT / 2);
    float acc = 0.f;
    for (int i = rlo; i < rhi; ++i) {
      acc += bfu(sdat[i * 128 + k]);
      if (i + 1 == rhi || sbag[i + 1] != sbag[i]) {
        atomicAdd(out + (((size_t)sbag[i]) << 7) + k, acc);
        acc = 0.f;
      }
    }
  } else {
    // ---- cache gather: 512B fp32 rows from cache_table ----
    const int cb = bid - ntt_blocks;
    const int base = cb * CHC;
    const int count = min(CHC, n - base);
    float* sfl = reinterpret_cast<float*>(sdat);
    if (tid < count) {
      sidx[tid] = cached_indices[base + tid];
      sbag[tid] = bag_search(cached_offsets, nbags, base + tid);
    }
    __syncthreads();
    if (count == CHC) {
#pragma unroll
      for (int j = 0; j < 4; ++j) {
        const int r2 = w * 8 + j * 2;                  // 2 rows per instruction
        const int row = r2 + (lane >> 5);
        const char* src = reinterpret_cast<const char*>(cache_table) +
                          (((size_t)sidx[row]) << 9) + ((lane & 31) << 4);
        gload_lds16(src, sfl + r2 * 128);
      }
    } else {
      for (int r = w; r < count; r += 4) {
        reinterpret_cast<float2*>(sfl + r * 128)[lane] =
            reinterpret_cast<const float2*>(cache_table + (((size_t)sidx[r]) << 7))[lane];
      }
    }
    __syncthreads();
    const int k = tid & 127, h = tid >> 7;
    const int rlo = h * (CHC / 2);
    const int rhi = min(count, rlo + CHC / 2);
    float acc = 0.f;
    for (int i = rlo; i < rhi; ++i) {
      acc += sfl[i * 128 + k];
      if (i + 1 == rhi || sbag[i + 1] != sbag[i]) {
        atomicAdd(out + (((size_t)sbag[i]) << 7) + k, acc);
        acc = 0.f;
      }
    }
  }
}

extern "C" void kernel_launch(void* const* d_in, const int* in_sizes, int n_in,
                              void* d_out, int out_size, void* d_ws, size_t ws_size,
                              hipStream_t stream) {
  const int* indices        = (const int*)d_in[0];
  const int* offsets        = (const int*)d_in[1];
  const int* cached_indices = (const int*)d_in[2];
  const int* cached_offsets = (const int*)d_in[3];
  const float* core0        = (const float*)d_in[4];
  const float* core1        = (const float*)d_in[5];
  const float* core2        = (const float*)d_in[6];
  const float* cache_table  = (const float*)d_in[7];
  float* out = (float*)d_out;

  const int n = in_sizes[0];             // 204800
  const int nbags = in_sizes[1] - 1;     // 4096

  u16* emb_t = (u16*)d_ws;                                   // 32,000,000 B
  float* chat = (float*)((char*)d_ws + 32000000);            // 57,600 B

  hipMemsetAsync(out, 0, (size_t)out_size * sizeof(float), stream);

  chat_kernel<<<50, 256, 0, stream>>>(core2, chat);
  build_emb_kernel<<<PAIRS, 512, 0, stream>>>(core0, core1, chat, emb_t);

  const int ntt = (n + CHT - 1) / CHT;   // 3200
  const int nc  = (n + CHC - 1) / CHC;   // 6400
  sum_kernel<<<ntt + nc, 256, 0, stream>>>(
      indices, offsets, cached_indices, cached_offsets, cache_table, emb_t,
      out, n, nbags, ntt);
}